// Round 6
// baseline (242.688 us; speedup 1.0000x reference)
//
#include <hip/hip_runtime.h>

// YOLO loss: preds (B,7,7,30) f32, labels (B,7,7,30) f32 -> scalar f32 (sum/B).
// R6: persistent grid (784 blocks x 256 thr, 4 cells/thread) with register
// double-buffer prefetch: iteration i+1's loads issue before iteration i's
// compute and live across the backedge -> compiler cannot sink them ->
// guaranteed ~31 loads in flight per wave during every compute phase.

#define BATCH 16384
#define S 7
#define C 30
#define NCELLS (BATCH * S * S)   // 802816
#define BLOCK 256
#define GRID 784
#define ITERS 4                   // 784*256*4 == 802816 exactly
#define STRIDE (GRID * BLOCK)     // 200704 cells

__device__ __forceinline__ float sq(float v) { return v * v; }

__device__ __forceinline__ float iou_box(float acx, float acy, float aw, float ah,
                                         float bcx, float bcy, float bw, float bh) {
    float ax0 = acx - aw * 0.5f, ax1 = acx + aw * 0.5f;
    float ay0 = acy - ah * 0.5f, ay1 = acy + ah * 0.5f;
    float bx0 = bcx - bw * 0.5f, bx1 = bcx + bw * 0.5f;
    float by0 = bcy - bh * 0.5f, by1 = bcy + bh * 0.5f;
    float iw = fmaxf(fminf(ax1, bx1) - fmaxf(ax0, bx0), 0.0f);
    float ih = fmaxf(fminf(ay1, by1) - fmaxf(ay0, by0), 0.0f);
    float inter = iw * ih;
    float denom = aw * ah + bw * bh - inter + 1e-10f;
    return inter / denom;
}

__device__ __forceinline__ int partner_cell(int cell) {
    int b   = cell / (S * S);
    int rem = cell - b * (S * S);
    int y   = rem / S;
    int x   = rem - y * S;
    return b * (S * S) + x * S + y;
}

__device__ __forceinline__ float cell_loss(const float2* tp, const float2* tl, float lb0) {
    float pv[C], lv[C];
    #pragma unroll
    for (int i = 0; i < 15; ++i) {
        pv[2 * i] = tp[i].x; pv[2 * i + 1] = tp[i].y;
        lv[2 * i] = tl[i].x; lv[2 * i + 1] = tl[i].y;
    }

    float iou1 = iou_box(pv[0], pv[1], pv[2], pv[3], lb0, lv[1], lv[2], lv[3]);
    float iou2 = iou_box(pv[5], pv[6], pv[7], pv[8], lb0, lv[1], lv[2], lv[3]);

    float b1 = 5.0f * (sq(pv[0] - lv[0]) + sq(pv[1] - lv[1]))
             + sq(sqrtf(pv[2]) - sqrtf(lv[2])) + sq(sqrtf(pv[3]) - sqrtf(lv[3]))
             + sq(iou1 - pv[4])
             + 0.5f * pv[9] * pv[9];

    float b2 = 5.0f * (sq(pv[5] - lv[5]) + sq(pv[6] - lv[6]))
             + sq(sqrtf(pv[7]) - sqrtf(lv[7])) + sq(sqrtf(pv[8]) - sqrtf(lv[8]))
             + sq(iou2 - pv[9])
             + 0.5f * pv[4] * pv[4];

    float cls = 0.0f;
    #pragma unroll
    for (int c = 10; c < C; ++c) cls += sq(lv[c] - pv[c]);

    float obj_loss   = ((iou1 > iou2) ? b1 : b2) + cls;
    float noobj_loss = 0.5f * (pv[4] * pv[4] + pv[9] * pv[9]);
    return (lv[4] == 1.0f) ? obj_loss : noobj_loss;
}

__global__ __launch_bounds__(BLOCK, 3) void yolo_partial_kernel(
        const float* __restrict__ preds,
        const float* __restrict__ labels,
        float* __restrict__ partials) {
    const int tid   = threadIdx.x;
    const int cell0 = blockIdx.x * BLOCK + tid;

    // ---- prefetch iteration 0 ----
    float2 tp[15], tl[15];
    float  lb0;
    {
        const float2* pG = reinterpret_cast<const float2*>(preds  + (size_t)cell0 * C);
        const float2* lG = reinterpret_cast<const float2*>(labels + (size_t)cell0 * C);
        #pragma unroll
        for (int i = 0; i < 15; ++i) tp[i] = pG[i];
        #pragma unroll
        for (int i = 0; i < 15; ++i) tl[i] = lG[i];
        lb0 = labels[(size_t)partner_cell(cell0) * C];
    }

    float acc = 0.0f;
    #pragma unroll
    for (int it = 0; it < ITERS; ++it) {
        float2 np[15], nl[15];
        float  nlb0 = 0.0f;
        if (it + 1 < ITERS) {
            int nc = cell0 + (it + 1) * STRIDE;
            const float2* pG = reinterpret_cast<const float2*>(preds  + (size_t)nc * C);
            const float2* lG = reinterpret_cast<const float2*>(labels + (size_t)nc * C);
            #pragma unroll
            for (int i = 0; i < 15; ++i) np[i] = pG[i];
            #pragma unroll
            for (int i = 0; i < 15; ++i) nl[i] = lG[i];
            nlb0 = labels[(size_t)partner_cell(nc) * C];
        }

        acc += cell_loss(tp, tl, lb0);   // consumes current buffer while next is in flight

        if (it + 1 < ITERS) {
            #pragma unroll
            for (int i = 0; i < 15; ++i) { tp[i] = np[i]; tl[i] = nl[i]; }
            lb0 = nlb0;
        }
    }

    // ---- reduction: wave shuffle -> LDS -> one store per block ----
    #pragma unroll
    for (int off = 32; off > 0; off >>= 1)
        acc += __shfl_down(acc, off, 64);

    __shared__ float wsum[BLOCK / 64];
    int lane = tid & 63;
    int wv   = tid >> 6;
    if (lane == 0) wsum[wv] = acc;
    __syncthreads();
    if (tid == 0) {
        partials[blockIdx.x] = wsum[0] + wsum[1] + wsum[2] + wsum[3];
    }
}

__global__ __launch_bounds__(BLOCK) void yolo_reduce_kernel(
        const float* __restrict__ partials,
        float* __restrict__ out) {
    const int tid = threadIdx.x;
    float s = 0.0f;
    for (int i = tid; i < GRID; i += BLOCK) s += partials[i];

    #pragma unroll
    for (int off = 32; off > 0; off >>= 1)
        s += __shfl_down(s, off, 64);

    __shared__ float wsum[BLOCK / 64];
    int lane = tid & 63;
    int wv   = tid >> 6;
    if (lane == 0) wsum[wv] = s;
    __syncthreads();
    if (tid == 0) {
        out[0] = (wsum[0] + wsum[1] + wsum[2] + wsum[3]) * (1.0f / (float)BATCH);
    }
}

extern "C" void kernel_launch(void* const* d_in, const int* in_sizes, int n_in,
                              void* d_out, int out_size, void* d_ws, size_t ws_size,
                              hipStream_t stream) {
    const float* preds  = (const float*)d_in[0];
    const float* labels = (const float*)d_in[1];
    float* out = (float*)d_out;
    float* partials = (float*)d_ws;   // GRID floats = 3136 B

    yolo_partial_kernel<<<GRID, BLOCK, 0, stream>>>(preds, labels, partials);
    yolo_reduce_kernel<<<1, BLOCK, 0, stream>>>(partials, out);
}

// Round 7
// 208.361 us; speedup vs baseline: 1.1647x; 1.1647x over previous
//
#include <hip/hip_runtime.h>

// YOLO loss: preds (B,7,7,30) f32, labels (B,7,7,30) f32 -> scalar f32 (sum/B).
// R7: exploit obj sparsity (15%). All cells need only labels[4], preds[4],
// preds[9] (3 float2 loads); the full 28-load obj path runs exec-masked under
// l4==1. Theory: env delivered-byte ceiling ~2.6 TB/s; cut bytes 240->~185/cell.

#define BATCH 16384
#define S 7
#define C 30
#define NCELLS (BATCH * S * S)   // 802816
#define BLOCK 256
#define NBLK (NCELLS / BLOCK)     // 3136

__device__ __forceinline__ float sq(float v) { return v * v; }

__device__ __forceinline__ float iou_box(float acx, float acy, float aw, float ah,
                                         float bcx, float bcy, float bw, float bh) {
    float ax0 = acx - aw * 0.5f, ax1 = acx + aw * 0.5f;
    float ay0 = acy - ah * 0.5f, ay1 = acy + ah * 0.5f;
    float bx0 = bcx - bw * 0.5f, bx1 = bcx + bw * 0.5f;
    float by0 = bcy - bh * 0.5f, by1 = bcy + bh * 0.5f;
    float iw = fmaxf(fminf(ax1, bx1) - fmaxf(ax0, bx0), 0.0f);
    float ih = fmaxf(fminf(ay1, by1) - fmaxf(ay0, by0), 0.0f);
    float inter = iw * ih;
    float denom = aw * ah + bw * bh - inter + 1e-10f;
    return inter / denom;
}

__global__ __launch_bounds__(BLOCK) void yolo_partial_kernel(
        const float* __restrict__ preds,
        const float* __restrict__ labels,
        float* __restrict__ partials) {
    const int tid  = threadIdx.x;
    const int cell = blockIdx.x * BLOCK + tid;

    const float* p = preds  + (size_t)cell * C;
    const float* l = labels + (size_t)cell * C;

    // ---- cheap path loads (all cells): l4(,l5), p4(,p5), p8,p9 ----
    float2 l45 = *reinterpret_cast<const float2*>(l + 4);
    float2 p45 = *reinterpret_cast<const float2*>(p + 4);
    float2 p89 = *reinterpret_cast<const float2*>(p + 8);

    float loss;
    if (l45.x == 1.0f) {
        // ---- obj path: remaining loads, exec-masked (~15% of lanes) ----
        float2 p01 = *reinterpret_cast<const float2*>(p + 0);
        float2 p23 = *reinterpret_cast<const float2*>(p + 2);
        float2 p67 = *reinterpret_cast<const float2*>(p + 6);
        float2 l01 = *reinterpret_cast<const float2*>(l + 0);
        float2 l23 = *reinterpret_cast<const float2*>(l + 2);
        float2 l67 = *reinterpret_cast<const float2*>(l + 6);
        float2 l89 = *reinterpret_cast<const float2*>(l + 8);

        // transposed label x-coord quirk: labels[b, x, y, 0]
        int b   = cell / (S * S);
        int rem = cell - b * (S * S);
        int y   = rem / S;
        int x   = rem - y * S;
        int pc  = b * (S * S) + x * S + y;
        float lb0 = labels[(size_t)pc * C];

        float iou1 = iou_box(p01.x, p01.y, p23.x, p23.y, lb0, l01.y, l23.x, l23.y);
        float iou2 = iou_box(p45.y, p67.x, p67.y, p89.x, lb0, l01.y, l23.x, l23.y);

        float b1 = 5.0f * (sq(p01.x - l01.x) + sq(p01.y - l01.y))
                 + sq(sqrtf(p23.x) - sqrtf(l23.x)) + sq(sqrtf(p23.y) - sqrtf(l23.y))
                 + sq(iou1 - p45.x)
                 + 0.5f * p89.y * p89.y;

        float b2 = 5.0f * (sq(p45.y - l45.y) + sq(p67.x - l67.x))
                 + sq(sqrtf(p67.y) - sqrtf(l67.y)) + sq(sqrtf(p89.x) - sqrtf(l89.x))
                 + sq(iou2 - p89.y)
                 + 0.5f * p45.x * p45.x;

        float cls = 0.0f;
        #pragma unroll
        for (int i = 0; i < 10; ++i) {
            float2 pc2 = *reinterpret_cast<const float2*>(p + 10 + 2 * i);
            float2 lc2 = *reinterpret_cast<const float2*>(l + 10 + 2 * i);
            cls += sq(lc2.x - pc2.x) + sq(lc2.y - pc2.y);
        }

        loss = ((iou1 > iou2) ? b1 : b2) + cls;
    } else {
        loss = 0.5f * (p45.x * p45.x + p89.y * p89.y);
    }

    // ---- reduction: wave shuffle -> LDS -> one store per block ----
    #pragma unroll
    for (int off = 32; off > 0; off >>= 1)
        loss += __shfl_down(loss, off, 64);

    __shared__ float wsum[BLOCK / 64];
    int lane = tid & 63;
    int wv   = tid >> 6;
    if (lane == 0) wsum[wv] = loss;
    __syncthreads();
    if (tid == 0) {
        partials[blockIdx.x] = wsum[0] + wsum[1] + wsum[2] + wsum[3];
    }
}

__global__ __launch_bounds__(BLOCK) void yolo_reduce_kernel(
        const float* __restrict__ partials,
        float* __restrict__ out) {
    const int tid = threadIdx.x;
    float s = 0.0f;
    for (int i = tid; i < NBLK; i += BLOCK) s += partials[i];

    #pragma unroll
    for (int off = 32; off > 0; off >>= 1)
        s += __shfl_down(s, off, 64);

    __shared__ float wsum[BLOCK / 64];
    int lane = tid & 63;
    int wv   = tid >> 6;
    if (lane == 0) wsum[wv] = s;
    __syncthreads();
    if (tid == 0) {
        out[0] = (wsum[0] + wsum[1] + wsum[2] + wsum[3]) * (1.0f / (float)BATCH);
    }
}

extern "C" void kernel_launch(void* const* d_in, const int* in_sizes, int n_in,
                              void* d_out, int out_size, void* d_ws, size_t ws_size,
                              hipStream_t stream) {
    const float* preds  = (const float*)d_in[0];
    const float* labels = (const float*)d_in[1];
    float* out = (float*)d_out;
    float* partials = (float*)d_ws;   // NBLK floats = 12.25 KB

    yolo_partial_kernel<<<NBLK, BLOCK, 0, stream>>>(preds, labels, partials);
    yolo_reduce_kernel<<<1, BLOCK, 0, stream>>>(partials, out);
}